// Round 6
// baseline (24.597 us; speedup 1.0000x reference)
//
#include <hip/hip_runtime.h>

typedef short s16x8 __attribute__((ext_vector_type(8)));
typedef float f32x4 __attribute__((ext_vector_type(4)));

__device__ __forceinline__ short f2bf(float f) {  // RNE f32->bf16
  union { float f; unsigned u; } cv;
  cv.f = f;
  unsigned u = cv.u;
  u = (u + 0x7FFFu + ((u >> 16) & 1u)) >> 16;
  return (short)u;
}
// pack two f32 -> bf16x2 by truncation (low elem = lo)
__device__ __forceinline__ unsigned pk2(float lo, float hi) {
  union { float f; unsigned u; } a, b;
  a.f = lo;
  b.f = hi;
  return (a.u >> 16) | (b.u & 0xFFFF0000u);
}

// ---------------------------------------------------------------------------
// K0: Mc_bf[(e*5+a)*128+m] = bf16( sum_n adj_w[e,m,n]*adj_a[a,n] )
// 20 blocks (e x mgroup) x 256 threads; 8 threads cooperate per m.
// ---------------------------------------------------------------------------
__global__ __launch_bounds__(256) void precomp_Mc(
    const float* __restrict__ adj_w, const float* __restrict__ adj_a,
    unsigned short* __restrict__ Mc_bf) {
  __shared__ float As[5][128];
  const int t = threadIdx.x;
  const int e = blockIdx.x >> 2, mg = blockIdx.x & 3;
  for (int idx = t; idx < 640; idx += 256) As[idx >> 7][idx & 127] = adj_a[idx];
  __syncthreads();
  const int m = mg * 32 + (t >> 3), ns = t & 7;
  const float* W = adj_w + (size_t)e * 16384 + (size_t)m * 128 + ns * 16;
  float acc[5] = {0.f, 0.f, 0.f, 0.f, 0.f};
#pragma unroll
  for (int it = 0; it < 4; ++it) {
    const float4 wv = *(const float4*)(W + it * 4);
    const float wa[4] = {wv.x, wv.y, wv.z, wv.w};
#pragma unroll
    for (int q = 0; q < 4; ++q) {
      const int n = ns * 16 + it * 4 + q;
#pragma unroll
      for (int a = 0; a < 5; ++a) acc[a] = fmaf(wa[q], As[a][n], acc[a]);
    }
  }
#pragma unroll
  for (int d = 1; d < 8; d <<= 1)
#pragma unroll
    for (int a = 0; a < 5; ++a) acc[a] += __shfl_xor(acc[a], d);
  if (ns == 0)
#pragma unroll
    for (int a = 0; a < 5; ++a)
      Mc_bf[(e * 5 + a) * 128 + m] = (unsigned short)f2bf(acc[a]);
}

// ---------------------------------------------------------------------------
// Fused: block = (b, row-half). Full hist of bfm[b] (register counters),
// msg = (P @ Mtab) via MFMA written transposed+swizzled to LDS, then
// out-half = adj-half @ msg via MFMA. adj loads issued at T0, consumed last.
// 512 blocks x 256 threads, ~55KB LDS -> 2 blocks/CU resident.
// ---------------------------------------------------------------------------
__global__ __launch_bounds__(256, 2) void fused_kernel(
    const int* __restrict__ bfm, const float* __restrict__ adj,
    const int* __restrict__ a_bfm, const unsigned short* __restrict__ Mc_bf,
    float* __restrict__ out) {
  __shared__ __align__(16) unsigned short msgsT[128 * 128];  // 32 KB
  __shared__ __align__(16) unsigned short P[128 * 40];       // 10 KB
  __shared__ __align__(16) unsigned short Mtab[32 * 136];    // 8.5 KB
  __shared__ unsigned red[4][32][4][2];                      // 4 KB
  const int b = blockIdx.x >> 1, h = blockIdx.x & 1, r0 = h * 64;
  const int t = threadIdx.x, w = t >> 6, l = t & 63, g = l >> 4, c = l & 15;

  // ---- T0: issue all global loads (bfm first, then meta, then adj) ----
  const int col4 = t & 31, rr = t >> 5;
  const int4* bp = (const int4*)bfm + (size_t)b * 4096 + col4;
  int4 bv[16];
#pragma unroll
  for (int it = 0; it < 8; ++it) bv[it] = bp[(size_t)(rr * 16 + it) * 32];
  // Mc table: 400 chunks of 8 bf16; thread t stages chunk t and (t<144) 256+t
  s16x8 mst0 = *(const s16x8*)&Mc_bf[t * 8];
  const bool hasM1 = t < 144;
  s16x8 mst1 = {0, 0, 0, 0, 0, 0, 0, 0};
  if (hasM1) mst1 = *(const s16x8*)&Mc_bf[(256 + t) * 8];
  int av = 0;
  if (t < 128) av = a_bfm[b * 128 + t];
#pragma unroll
  for (int it = 8; it < 16; ++it) bv[it] = bp[(size_t)(rr * 16 + it) * 32];
  const float* arow = adj + (size_t)b * 16384 + (size_t)(r0 + w * 16 + c) * 128;
  float4 a0[4], a1[4];
#pragma unroll
  for (int kk = 0; kk < 4; ++kk) {
    a0[kk] = *(const float4*)(arow + (kk * 4 + g) * 8);
    a1[kk] = *(const float4*)(arow + (kk * 4 + g) * 8 + 4);
  }

  // ---- LDS init (no global dep) ----
  for (int idx = t; idx < 640; idx += 256)
    ((uint4*)P)[idx] = make_uint4(0u, 0u, 0u, 0u);
  for (int idx = t; idx < 7 * 136; idx += 256) Mtab[25 * 136 + idx] = 0;

  // ---- histogram: 16 rows x 4 cols per thread, byte-packed counts ----
  unsigned pA[4] = {0, 0, 0, 0}, pB[4] = {0, 0, 0, 0};
#pragma unroll
  for (int it = 0; it < 16; ++it) {
    const int vv[4] = {bv[it].x, bv[it].y, bv[it].z, bv[it].w};
#pragma unroll
    for (int jj = 0; jj < 4; ++jj) {
      pA[jj] += (unsigned)(vv[jj] == 1) + ((unsigned)(vv[jj] == 2) << 8) +
                ((unsigned)(vv[jj] == 3) << 16) + ((unsigned)(vv[jj] == 4) << 24);
      pB[jj] += (unsigned)(vv[jj] == 5);
    }
  }
#pragma unroll
  for (int jj = 0; jj < 4; ++jj) {  // lanes l and l^32 share columns
    pA[jj] += (unsigned)__shfl_xor((int)pA[jj], 32);
    pB[jj] += (unsigned)__shfl_xor((int)pB[jj], 32);
  }
  if (l < 32) {
#pragma unroll
    for (int jj = 0; jj < 4; ++jj) {
      red[w][l][jj][0] = pA[jj];
      red[w][l][jj][1] = pB[jj];
    }
  }
  // Mtab -> LDS (waits its own vmcnt; bfm already consumed, adj stays queued)
  *(s16x8*)&Mtab[(t >> 4) * 136 + (t & 15) * 8] = mst0;
  if (hasM1) {
    const int ch = 256 + t;
    *(s16x8*)&Mtab[(ch >> 4) * 136 + (ch & 15) * 8] = mst1;
  }
  __syncthreads();

  // ---- final count reduce + P scatter (j == t for t<128) ----
  if (t < 128 && av > 0) {
    unsigned A = 0, B = 0;
    const int c4i = t >> 2, jj = t & 3;
#pragma unroll
    for (int w2 = 0; w2 < 4; ++w2) {
      A += red[w2][c4i][jj][0];
      B += red[w2][c4i][jj][1];
    }
    const int ai = av - 1;
    unsigned short* Pr = &P[t * 40];
    Pr[ai] = (unsigned short)f2bf((float)(A & 255u));
    Pr[5 + ai] = (unsigned short)f2bf((float)((A >> 8) & 255u));
    Pr[10 + ai] = (unsigned short)f2bf((float)((A >> 16) & 255u));
    Pr[15 + ai] = (unsigned short)f2bf((float)(A >> 24));
    Pr[20 + ai] = (unsigned short)f2bf((float)(B & 255u));
  }
  __syncthreads();

  // ---- msg MFMA: wave w -> m-strip [w*32,+32); C-layout writes msgsT ----
  {
    const int m0 = w * 32;
    s16x8 bfr[2];
#pragma unroll
    for (int ct = 0; ct < 2; ++ct)
#pragma unroll
      for (int e = 0; e < 8; ++e)
        bfr[ct][e] = (short)Mtab[(g * 8 + e) * 136 + m0 + ct * 16 + c];
#pragma unroll
    for (int jt = 0; jt < 8; ++jt) {
      const s16x8 afr = *(const s16x8*)&P[(jt * 16 + c) * 40 + g * 8];
#pragma unroll
      for (int ct = 0; ct < 2; ++ct) {
        f32x4 acc = {0.f, 0.f, 0.f, 0.f};
        acc = __builtin_amdgcn_mfma_f32_16x16x32_bf16(afr, bfr[ct], acc, 0, 0, 0);
        const int m = m0 + ct * 16 + c;
        unsigned short* dst =
            &msgsT[m * 128 + (((jt * 2 + (g >> 1)) ^ (m & 15)) << 3) + (g & 1) * 4];
#pragma unroll
        for (int q = 0; q < 4; ++q) dst[q] = (unsigned short)f2bf(acc[q]);
      }
    }
  }

  // ---- pack A (adj loads issued at T0 have long landed) ----
  s16x8 apk[4];
#pragma unroll
  for (int kk = 0; kk < 4; ++kk) {
    unsigned* pu = (unsigned*)&apk[kk];
    pu[0] = pk2(a0[kk].x, a0[kk].y);
    pu[1] = pk2(a0[kk].z, a0[kk].w);
    pu[2] = pk2(a1[kk].x, a1[kk].y);
    pu[3] = pk2(a1[kk].z, a1[kk].w);
  }
  __syncthreads();

  // ---- GEMM2: wave w -> rows [r0+w*16,+16), all 128 m. Zero VMEM reads ----
  f32x4 acc2[8];
#pragma unroll
  for (int mt = 0; mt < 8; ++mt) acc2[mt] = (f32x4){0.f, 0.f, 0.f, 0.f};
#pragma unroll
  for (int kk = 0; kk < 4; ++kk) {
#pragma unroll
    for (int mt = 0; mt < 8; ++mt) {
      const int m = mt * 16 + c;
      const s16x8 bfr2 =
          *(const s16x8*)&msgsT[m * 128 + (((kk * 4 + g) ^ (m & 15)) << 3)];
      acc2[mt] =
          __builtin_amdgcn_mfma_f32_16x16x32_bf16(apk[kk], bfr2, acc2[mt], 0, 0, 0);
    }
  }
  float* ob = out + (size_t)b * 16384 + (size_t)(r0 + w * 16) * 128;
#pragma unroll
  for (int mt = 0; mt < 8; ++mt)
#pragma unroll
    for (int q = 0; q < 4; ++q)
      ob[(g * 4 + q) * 128 + mt * 16 + c] = acc2[mt][q];
}

extern "C" void kernel_launch(void* const* d_in, const int* in_sizes, int n_in,
                              void* d_out, int out_size, void* d_ws,
                              size_t ws_size, hipStream_t stream) {
  // inputs: 0=afm(unused), 1=bfm, 2=a_bfm, 3=adj, 4=adj_w, 5=adj_a
  const int* bfm = (const int*)d_in[1];
  const int* a_bfm = (const int*)d_in[2];
  const float* adj = (const float*)d_in[3];
  const float* adj_w = (const float*)d_in[4];
  const float* adj_a = (const float*)d_in[5];
  float* out = (float*)d_out;

  unsigned short* Mc_bf = (unsigned short*)d_ws;  // 25*128 bf16 = 6.4 KB

  precomp_Mc<<<dim3(20), dim3(256), 0, stream>>>(adj_w, adj_a, Mc_bf);
  fused_kernel<<<dim3(512), dim3(256), 0, stream>>>(bfm, adj, a_bfm, Mc_bf,
                                                    out);
}

// Round 7
// 17.858 us; speedup vs baseline: 1.3774x; 1.3774x over previous
//
#include <hip/hip_runtime.h>

typedef short s16x8 __attribute__((ext_vector_type(8)));
typedef float f32x4 __attribute__((ext_vector_type(4)));

__device__ __forceinline__ short f2bf(float f) {  // RNE f32->bf16
  union { float f; unsigned u; } cv;
  cv.f = f;
  unsigned u = cv.u;
  u = (u + 0x7FFFu + ((u >> 16) & 1u)) >> 16;
  return (short)u;
}
// pack two f32 -> bf16x2 by truncation (low elem = lo)
__device__ __forceinline__ unsigned pk2(float lo, float hi) {
  union { float f; unsigned u; } a, b;
  a.f = lo;
  b.f = hi;
  return (a.u >> 16) | (b.u & 0xFFFF0000u);
}

// ---------------------------------------------------------------------------
// K1: blocks 0..1023 = histogram (b, 32-col group) -> cnt_g (byte-packed).
//     blocks 1024..1043 = McT table (TRANSPOSED): McT[m*40 + e*5 + a] =
//     bf16(sum_n W[e,m,n]*A[a,n]); rows r in [25,40) zeroed (by e==0 blocks).
// ---------------------------------------------------------------------------
__global__ __launch_bounds__(256, 4) void hist_mc_kernel(
    const int* __restrict__ bfm, const float* __restrict__ adj_w,
    const float* __restrict__ adj_a, uint2* __restrict__ cnt_g,
    unsigned short* __restrict__ McT) {
  __shared__ unsigned red[4][8][4][2];
  __shared__ float As[5][128];
  const int t = threadIdx.x;

  if (blockIdx.x >= 1024) {  // ---- McT blocks ----
    const int bi = blockIdx.x - 1024;
    const int e = bi >> 2, mg = bi & 3;
    for (int idx = t; idx < 640; idx += 256) As[idx >> 7][idx & 127] = adj_a[idx];
    __syncthreads();
    const int m = mg * 32 + (t >> 3), ns = t & 7;
    const float* W = adj_w + (size_t)e * 16384 + (size_t)m * 128 + ns * 16;
    float acc[5] = {0.f, 0.f, 0.f, 0.f, 0.f};
#pragma unroll
    for (int it = 0; it < 4; ++it) {
      const float4 wv = *(const float4*)(W + it * 4);
      const float wa[4] = {wv.x, wv.y, wv.z, wv.w};
#pragma unroll
      for (int q = 0; q < 4; ++q) {
        const int n = ns * 16 + it * 4 + q;
#pragma unroll
        for (int a = 0; a < 5; ++a) acc[a] = fmaf(wa[q], As[a][n], acc[a]);
      }
    }
#pragma unroll
    for (int d = 1; d < 8; d <<= 1)
#pragma unroll
      for (int a = 0; a < 5; ++a) acc[a] += __shfl_xor(acc[a], d);
    if (ns == 0) {
#pragma unroll
      for (int a = 0; a < 5; ++a)
        McT[m * 40 + e * 5 + a] = (unsigned short)f2bf(acc[a]);
      if (e == 0)
#pragma unroll
        for (int r = 25; r < 40; ++r) McT[m * 40 + r] = 0;
    }
    return;
  }

  // ---- hist blocks (r4-proven) ----
  const int b = blockIdx.x >> 2, jg = blockIdx.x & 3;
  const int w = t >> 6, l = t & 63, c4 = l & 7, rr = l >> 3;
  const int4* bp = (const int4*)bfm + (size_t)b * 4096 + jg * 8 + c4;
  unsigned pA[4] = {0, 0, 0, 0}, pB[4] = {0, 0, 0, 0};
#pragma unroll
  for (int it = 0; it < 4; ++it) {
    const int i = it * 32 + w * 8 + rr;
    const int4 v = bp[(size_t)i * 32];
    const int vv[4] = {v.x, v.y, v.z, v.w};
#pragma unroll
    for (int jj = 0; jj < 4; ++jj) {
      pA[jj] += (unsigned)(vv[jj] == 1) + ((unsigned)(vv[jj] == 2) << 8) +
                ((unsigned)(vv[jj] == 3) << 16) + ((unsigned)(vv[jj] == 4) << 24);
      pB[jj] += (unsigned)(vv[jj] == 5);
    }
  }
#pragma unroll
  for (int d = 8; d < 64; d <<= 1)
#pragma unroll
    for (int jj = 0; jj < 4; ++jj) {
      pA[jj] += (unsigned)__shfl_xor((int)pA[jj], d);
      pB[jj] += (unsigned)__shfl_xor((int)pB[jj], d);
    }
  if (rr == 0)
#pragma unroll
    for (int jj = 0; jj < 4; ++jj) {
      red[w][c4][jj][0] = pA[jj];
      red[w][c4][jj][1] = pB[jj];
    }
  __syncthreads();
  if (t < 32) {
    unsigned A = 0, B = 0;
    const int cc = t >> 2, jj = t & 3;
#pragma unroll
    for (int w2 = 0; w2 < 4; ++w2) {
      A += red[w2][cc][jj][0];
      B += red[w2][cc][jj][1];
    }
    cnt_g[b * 128 + jg * 32 + t] = make_uint2(A, B);
  }
}

// ---------------------------------------------------------------------------
// K2: out[b, rows, :] = (adj@P) @ McT via two skinny MFMA stages.
//   Q = adj(16x128 per wave) @ P(128x32): 8 MFMA; P in LDS transposed
//   (Pt[r][j], 16B-chunk XOR swizzle -> conflict-free b128 B-frags).
//   out = Q(16x32) @ Mtab(32x128): 8 MFMA; Mt[m][r] rows -> b128 B-frags.
//   adj loads issued at T0 into A-frag registers; raw s_barrier +
//   lgkmcnt-only waits keep them in flight across both barriers.
// grid 1024 (b x quarter) x 128 threads, ~21 KB LDS.
// ---------------------------------------------------------------------------
__global__ __launch_bounds__(128, 3) void skinny_kernel(
    const float* __restrict__ adj, const int* __restrict__ a_bfm,
    const uint2* __restrict__ cnt_g, const unsigned short* __restrict__ McT,
    float* __restrict__ out) {
  __shared__ __align__(16) unsigned short Pt[32 * 128];    // 8 KB, XOR-swz
  __shared__ __align__(16) unsigned short Mt[128 * 40];    // 10 KB
  __shared__ __align__(16) unsigned short Qs[2 * 16 * 40]; // 2.5 KB
  const int bq = blockIdx.x, b = bq >> 2, qq = bq & 3;
  const int t = threadIdx.x, w = t >> 6, l = t & 63, g = l >> 4, c = l & 15;
  const int row0 = qq * 32 + w * 16;

  // ---- T0: small loads first (consumed first), adj last (consumed last) ----
  const uint2 cc2 = cnt_g[b * 128 + t];
  const int av = a_bfm[b * 128 + t];
  s16x8 mst[5];
#pragma unroll
  for (int i = 0; i < 5; ++i) mst[i] = *(const s16x8*)&McT[(i * 128 + t) * 8];
  const float* arow = adj + (size_t)b * 16384 + (size_t)(row0 + c) * 128;
  float4 a0[4], a1[4];
#pragma unroll
  for (int kk = 0; kk < 4; ++kk) {
    a0[kk] = *(const float4*)(arow + kk * 32 + g * 8);
    a1[kk] = *(const float4*)(arow + kk * 32 + g * 8 + 4);
  }

  // ---- zero Pt; stage Mt (waits mst via counted vmcnt; adj stays queued) ---
#pragma unroll
  for (int i = 0; i < 4; ++i)
    ((uint4*)Pt)[i * 128 + t] = make_uint4(0u, 0u, 0u, 0u);
#pragma unroll
  for (int i = 0; i < 5; ++i) *(s16x8*)&Mt[(i * 128 + t) * 8] = mst[i];
  asm volatile("s_waitcnt lgkmcnt(0)" ::: "memory");
  __builtin_amdgcn_s_barrier();

  // ---- scatter P^T: Pt[r][j=t] = cnt_e(j), r=(e-1)*5+ai, XOR-swz chunks ----
  if (av > 0) {
    const int ai = av - 1;
    const int chunk = t >> 3, off = t & 7;
    const float cf[5] = {(float)(cc2.x & 255u), (float)((cc2.x >> 8) & 255u),
                         (float)((cc2.x >> 16) & 255u), (float)(cc2.x >> 24),
                         (float)(cc2.y & 255u)};
#pragma unroll
    for (int ei = 0; ei < 5; ++ei) {
      const int r = ei * 5 + ai;
      Pt[r * 128 + ((chunk ^ (r & 15)) << 3) + off] =
          (unsigned short)f2bf(cf[ei]);
    }
  }
  asm volatile("s_waitcnt lgkmcnt(0)" ::: "memory");
  __builtin_amdgcn_s_barrier();

  // ---- stage 1: Q = adj @ P  (2 col-tiles x 4 k-chunks = 8 MFMA) ----
  // B1-frag: lane needs P[k=kk*32+g*8+e][n=ct*16+c] = Pt[n][k] (b128, swz)
  s16x8 bP[4][2];
#pragma unroll
  for (int kk = 0; kk < 4; ++kk)
#pragma unroll
    for (int ct = 0; ct < 2; ++ct) {
      const int r = ct * 16 + c;
      bP[kk][ct] = *(const s16x8*)&Pt[r * 128 + (((kk * 4 + g) ^ (r & 15)) << 3)];
    }
  // pack adj A-frags (vmcnt(0) lands here; issued at T0, well covered)
  s16x8 apk[4];
#pragma unroll
  for (int kk = 0; kk < 4; ++kk) {
    unsigned* pu = (unsigned*)&apk[kk];
    pu[0] = pk2(a0[kk].x, a0[kk].y);
    pu[1] = pk2(a0[kk].z, a0[kk].w);
    pu[2] = pk2(a1[kk].x, a1[kk].y);
    pu[3] = pk2(a1[kk].z, a1[kk].w);
  }
  f32x4 accQ[2] = {{0.f, 0.f, 0.f, 0.f}, {0.f, 0.f, 0.f, 0.f}};
#pragma unroll
  for (int kk = 0; kk < 4; ++kk)
#pragma unroll
    for (int ct = 0; ct < 2; ++ct)
      accQ[ct] =
          __builtin_amdgcn_mfma_f32_16x16x32_bf16(apk[kk], bP[kk][ct], accQ[ct], 0, 0, 0);

  // ---- transpose Q through wave-local LDS (no cross-wave barrier) ----
  // C-layout: lane holds Q[row=g*4+q][col=ct*16+c]; A2 needs Q[row=c][k]
  unsigned short* qsw = &Qs[w * 16 * 40];
#pragma unroll
  for (int ct = 0; ct < 2; ++ct)
#pragma unroll
    for (int q = 0; q < 4; ++q)
      qsw[(g * 4 + q) * 40 + ct * 16 + c] = (unsigned short)f2bf(accQ[ct][q]);
  // lgkmcnt(0) inserted by compiler before dependent read below
  const s16x8 aQ = *(const s16x8*)&qsw[c * 40 + g * 8];

  // ---- stage 2: out = Q @ Mtab  (8 col-tiles x 1 k-chunk = 8 MFMA) ----
  float* ob = out + (size_t)b * 16384 + (size_t)row0 * 128;
#pragma unroll
  for (int mt = 0; mt < 8; ++mt) {
    const s16x8 bM = *(const s16x8*)&Mt[(mt * 16 + c) * 40 + g * 8];
    f32x4 acc2 = {0.f, 0.f, 0.f, 0.f};
    acc2 = __builtin_amdgcn_mfma_f32_16x16x32_bf16(aQ, bM, acc2, 0, 0, 0);
#pragma unroll
    for (int q = 0; q < 4; ++q)
      ob[(g * 4 + q) * 128 + mt * 16 + c] = acc2[q];
  }
}

extern "C" void kernel_launch(void* const* d_in, const int* in_sizes, int n_in,
                              void* d_out, int out_size, void* d_ws,
                              size_t ws_size, hipStream_t stream) {
  // inputs: 0=afm(unused), 1=bfm, 2=a_bfm, 3=adj, 4=adj_w, 5=adj_a
  const int* bfm = (const int*)d_in[1];
  const int* a_bfm = (const int*)d_in[2];
  const float* adj = (const float*)d_in[3];
  const float* adj_w = (const float*)d_in[4];
  const float* adj_a = (const float*)d_in[5];
  float* out = (float*)d_out;

  unsigned short* McT = (unsigned short*)d_ws;    // 128*40 bf16 = 10.24 KB
  uint2* cnt_g = (uint2*)((char*)d_ws + 16384);   // 256*128*8B = 256 KB

  hist_mc_kernel<<<dim3(1044), dim3(256), 0, stream>>>(bfm, adj_w, adj_a,
                                                       cnt_g, McT);
  skinny_kernel<<<dim3(1024), dim3(128), 0, stream>>>(adj, a_bfm, cnt_g, McT,
                                                      out);
}

// Round 8
// 17.083 us; speedup vs baseline: 1.4398x; 1.0453x over previous
//
#include <hip/hip_runtime.h>

typedef short s16x8 __attribute__((ext_vector_type(8)));
typedef float f32x4 __attribute__((ext_vector_type(4)));

__device__ __forceinline__ short f2bf(float f) {  // RNE f32->bf16
  union { float f; unsigned u; } cv;
  cv.f = f;
  unsigned u = cv.u;
  u = (u + 0x7FFFu + ((u >> 16) & 1u)) >> 16;
  return (short)u;
}
// pack two f32 -> bf16x2 by truncation (low elem = lo)
__device__ __forceinline__ unsigned pk2(float lo, float hi) {
  union { float f; unsigned u; } a, b;
  a.f = lo;
  b.f = hi;
  return (a.u >> 16) | (b.u & 0xFFFF0000u);
}

// ---------------------------------------------------------------------------
// K1: blocks 0..19 = McT table (transposed, bf16): McT[m*40 + e*5 + a] =
//     bf16(sum_n W[e,m,n]*A[a,n]); rows [25,40) zeroed by e==0 blocks.
//     blocks 20..531 = histogram (b, row-half): CONTIGUOUS 32KB read,
//     partial counts -> cnt_h[(b*2+h)*128 + j] (uint2, byte-packed, <=64).
// ---------------------------------------------------------------------------
__global__ __launch_bounds__(256, 4) void hist_mc_kernel(
    const int* __restrict__ bfm, const float* __restrict__ adj_w,
    const float* __restrict__ adj_a, uint2* __restrict__ cnt_h,
    unsigned short* __restrict__ McT) {
  __shared__ unsigned red[4][32][4][2];
  __shared__ float As[5][128];
  const int t = threadIdx.x;

  if (blockIdx.x < 20) {  // ---- McT blocks ----
    const int bi = blockIdx.x;
    const int e = bi >> 2, mg = bi & 3;
    for (int idx = t; idx < 640; idx += 256) As[idx >> 7][idx & 127] = adj_a[idx];
    __syncthreads();
    const int m = mg * 32 + (t >> 3), ns = t & 7;
    const float* W = adj_w + (size_t)e * 16384 + (size_t)m * 128 + ns * 16;
    float acc[5] = {0.f, 0.f, 0.f, 0.f, 0.f};
#pragma unroll
    for (int it = 0; it < 4; ++it) {
      const float4 wv = *(const float4*)(W + it * 4);
      const float wa[4] = {wv.x, wv.y, wv.z, wv.w};
#pragma unroll
      for (int q = 0; q < 4; ++q) {
        const int n = ns * 16 + it * 4 + q;
#pragma unroll
        for (int a = 0; a < 5; ++a) acc[a] = fmaf(wa[q], As[a][n], acc[a]);
      }
    }
#pragma unroll
    for (int d = 1; d < 8; d <<= 1)
#pragma unroll
      for (int a = 0; a < 5; ++a) acc[a] += __shfl_xor(acc[a], d);
    if (ns == 0) {
#pragma unroll
      for (int a = 0; a < 5; ++a)
        McT[m * 40 + e * 5 + a] = (unsigned short)f2bf(acc[a]);
      if (e == 0)
#pragma unroll
        for (int r = 25; r < 40; ++r) McT[m * 40 + r] = 0;
    }
    return;
  }

  // ---- hist blocks: contiguous 1KB-per-wave reads ----
  const int idx2 = blockIdx.x - 20;
  const int b = idx2 >> 1, hh = idx2 & 1;
  const int w = t >> 6, l = t & 63;
  // thread t reads int4 at flat position it*1024 + t within the 32KB half;
  // its columns are fixed: j0 = (t&31)*4 .. +3
  const int4* bp = (const int4*)bfm + (size_t)b * 4096 + hh * 2048;
  unsigned pA[4] = {0, 0, 0, 0}, pB[4] = {0, 0, 0, 0};
#pragma unroll
  for (int it = 0; it < 8; ++it) {
    const int4 v = bp[it * 256 + t];
    const int vv[4] = {v.x, v.y, v.z, v.w};
#pragma unroll
    for (int jj = 0; jj < 4; ++jj) {
      pA[jj] += (unsigned)(vv[jj] == 1) + ((unsigned)(vv[jj] == 2) << 8) +
                ((unsigned)(vv[jj] == 3) << 16) + ((unsigned)(vv[jj] == 4) << 24);
      pB[jj] += (unsigned)(vv[jj] == 5);
    }
  }
#pragma unroll
  for (int jj = 0; jj < 4; ++jj) {  // lanes l and l^32 share columns
    pA[jj] += (unsigned)__shfl_xor((int)pA[jj], 32);
    pB[jj] += (unsigned)__shfl_xor((int)pB[jj], 32);
  }
  if (l < 32) {
#pragma unroll
    for (int jj = 0; jj < 4; ++jj) {
      red[w][l][jj][0] = pA[jj];
      red[w][l][jj][1] = pB[jj];
    }
  }
  __syncthreads();
  if (t < 128) {
    unsigned A = 0, B = 0;
    const int cc = t >> 2, jj = t & 3;
#pragma unroll
    for (int w2 = 0; w2 < 4; ++w2) {
      A += red[w2][cc][jj][0];
      B += red[w2][cc][jj][1];
    }
    cnt_h[(b * 2 + hh) * 128 + t] = make_uint2(A, B);  // bytes <= 64
  }
}

// ---------------------------------------------------------------------------
// K2: out[b, h*64 .. +64, :] = (adj@P) @ McT, two skinny MFMA stages.
// 512 blocks (b, half) x 256 threads (4 waves, 16 rows each), ~23 KB LDS.
// adj loads issued at T0 into registers; lgkmcnt-only waits + raw s_barrier
// keep them in flight until the pack step.
// ---------------------------------------------------------------------------
__global__ __launch_bounds__(256, 2) void skinny_kernel(
    const float* __restrict__ adj, const int* __restrict__ a_bfm,
    const uint2* __restrict__ cnt_h, const unsigned short* __restrict__ McT,
    float* __restrict__ out) {
  __shared__ __align__(16) unsigned short Pt[32 * 128];     // 8 KB, XOR-swz
  __shared__ __align__(16) unsigned short Mt[128 * 40];     // 10 KB
  __shared__ __align__(16) unsigned short Qs[4 * 16 * 40];  // 5 KB
  const int bh = blockIdx.x, b = bh >> 1, hh = bh & 1;
  const int t = threadIdx.x, w = t >> 6, l = t & 63, g = l >> 4, c = l & 15;
  const int row0 = hh * 64 + w * 16;

  // ---- T0: small loads first (consumed first), adj last (consumed last) ----
  uint2 h0 = make_uint2(0u, 0u), h1 = make_uint2(0u, 0u);
  int av = 0;
  if (t < 128) {
    h0 = cnt_h[(b * 2 + 0) * 128 + t];
    h1 = cnt_h[(b * 2 + 1) * 128 + t];
    av = a_bfm[b * 128 + t];
  }
  s16x8 mst0 = *(const s16x8*)&McT[t * 8];
  s16x8 mst1 = *(const s16x8*)&McT[(256 + t) * 8];
  s16x8 mst2 = {0, 0, 0, 0, 0, 0, 0, 0};
  if (t < 128) mst2 = *(const s16x8*)&McT[(512 + t) * 8];
  const float* arow = adj + (size_t)b * 16384 + (size_t)(row0 + c) * 128;
  float4 a0[4], a1[4];
#pragma unroll
  for (int kk = 0; kk < 4; ++kk) {
    a0[kk] = *(const float4*)(arow + kk * 32 + g * 8);
    a1[kk] = *(const float4*)(arow + kk * 32 + g * 8 + 4);
  }

  // ---- zero Pt; stage Mt (vmcnt waits only to mst; adj stays queued) ----
#pragma unroll
  for (int i = 0; i < 2; ++i)
    ((uint4*)Pt)[i * 256 + t] = make_uint4(0u, 0u, 0u, 0u);
  *(s16x8*)&Mt[t * 8] = mst0;
  *(s16x8*)&Mt[(256 + t) * 8] = mst1;
  if (t < 128) *(s16x8*)&Mt[(512 + t) * 8] = mst2;
  asm volatile("s_waitcnt lgkmcnt(0)" ::: "memory");
  __builtin_amdgcn_s_barrier();

  // ---- scatter P^T: Pt[r][j=t] = cnt_e(j), r=(e-1)*5+ai, XOR-swz chunks ----
  if (t < 128 && av > 0) {
    const unsigned cx = h0.x + h1.x;  // byte-packed add, bytes <= 128
    const unsigned cy = h0.y + h1.y;
    const int ai = av - 1;
    const int chunk = t >> 3, off = t & 7;
    const float cf[5] = {(float)(cx & 255u), (float)((cx >> 8) & 255u),
                         (float)((cx >> 16) & 255u), (float)(cx >> 24),
                         (float)(cy & 255u)};
#pragma unroll
    for (int ei = 0; ei < 5; ++ei) {
      const int r = ei * 5 + ai;
      Pt[r * 128 + ((chunk ^ (r & 15)) << 3) + off] =
          (unsigned short)f2bf(cf[ei]);
    }
  }
  asm volatile("s_waitcnt lgkmcnt(0)" ::: "memory");
  __builtin_amdgcn_s_barrier();

  // ---- stage 1: Q = adj @ P  (2 col-tiles x 4 k-chunks = 8 MFMA) ----
  s16x8 bP[4][2];
#pragma unroll
  for (int kk = 0; kk < 4; ++kk)
#pragma unroll
    for (int ct = 0; ct < 2; ++ct) {
      const int r = ct * 16 + c;
      bP[kk][ct] = *(const s16x8*)&Pt[r * 128 + (((kk * 4 + g) ^ (r & 15)) << 3)];
    }
  // pack adj A-frags (vmcnt(0) lands here; loads issued at T0, well covered)
  s16x8 apk[4];
#pragma unroll
  for (int kk = 0; kk < 4; ++kk) {
    unsigned* pu = (unsigned*)&apk[kk];
    pu[0] = pk2(a0[kk].x, a0[kk].y);
    pu[1] = pk2(a0[kk].z, a0[kk].w);
    pu[2] = pk2(a1[kk].x, a1[kk].y);
    pu[3] = pk2(a1[kk].z, a1[kk].w);
  }
  f32x4 accQ[2] = {{0.f, 0.f, 0.f, 0.f}, {0.f, 0.f, 0.f, 0.f}};
#pragma unroll
  for (int kk = 0; kk < 4; ++kk)
#pragma unroll
    for (int ct = 0; ct < 2; ++ct)
      accQ[ct] = __builtin_amdgcn_mfma_f32_16x16x32_bf16(apk[kk], bP[kk][ct],
                                                         accQ[ct], 0, 0, 0);

  // ---- transpose Q through wave-local LDS (no cross-wave barrier) ----
  unsigned short* qsw = &Qs[w * 16 * 40];
#pragma unroll
  for (int ct = 0; ct < 2; ++ct)
#pragma unroll
    for (int q = 0; q < 4; ++q)
      qsw[(g * 4 + q) * 40 + ct * 16 + c] = (unsigned short)f2bf(accQ[ct][q]);
  const s16x8 aQ = *(const s16x8*)&qsw[c * 40 + g * 8];

  // ---- stage 2: out = Q @ Mtab  (8 col-tiles x 1 k-chunk = 8 MFMA) ----
  float* ob = out + (size_t)b * 16384 + (size_t)row0 * 128;
#pragma unroll
  for (int mt = 0; mt < 8; ++mt) {
    const s16x8 bM = *(const s16x8*)&Mt[(mt * 16 + c) * 40 + g * 8];
    f32x4 acc2 = {0.f, 0.f, 0.f, 0.f};
    acc2 = __builtin_amdgcn_mfma_f32_16x16x32_bf16(aQ, bM, acc2, 0, 0, 0);
#pragma unroll
    for (int q = 0; q < 4; ++q)
      ob[(g * 4 + q) * 128 + mt * 16 + c] = acc2[q];
  }
}

extern "C" void kernel_launch(void* const* d_in, const int* in_sizes, int n_in,
                              void* d_out, int out_size, void* d_ws,
                              size_t ws_size, hipStream_t stream) {
  // inputs: 0=afm(unused), 1=bfm, 2=a_bfm, 3=adj, 4=adj_w, 5=adj_a
  const int* bfm = (const int*)d_in[1];
  const int* a_bfm = (const int*)d_in[2];
  const float* adj = (const float*)d_in[3];
  const float* adj_w = (const float*)d_in[4];
  const float* adj_a = (const float*)d_in[5];
  float* out = (float*)d_out;

  unsigned short* McT = (unsigned short*)d_ws;   // 128*40 bf16 = 10.24 KB
  uint2* cnt_h = (uint2*)((char*)d_ws + 16384);  // 256*2*128*8B = 512 KB

  hist_mc_kernel<<<dim3(532), dim3(256), 0, stream>>>(bfm, adj_w, adj_a,
                                                      cnt_h, McT);
  skinny_kernel<<<dim3(512), dim3(256), 0, stream>>>(adj, a_bfm, cnt_h, McT,
                                                     out);
}